// Round 17
// baseline (30.865 us; speedup 1.0000x reference)
//
#include <hip/hip_runtime.h>

// SymbolicTraversal: out[b, n] = max(0, max_{e: type[e]==r_index[b], dst[e]==n} h[b, src[e]])
//
// R16: bf16 value-in-record — phase2 has ZERO gathers.
//   phase1: 512 x 1024, stream edges (plain loads, R15 win), filter via
//           relation->batch bitmask, gather v=h[b][src] (overlaps stream under TLP),
//           drop v<=0, pack rec = (local_dst << 16) | bf16_rne(v) into per-bucket
//           LDS queues, flush as 64B segments {count, <=15 recs}. No global atomics.
//   phase2: 400 x 1024, batch-major decode (XCD-local, R13 win), wave-shaped
//           (segment,word) scan, atomicMax(&slice[ld], rec<<16) — bf16<<16 is a
//           positive-f32 bit pattern so int max == float max — then coalesced store.
// Numerics: bf16 RNE error <= ~0.002 on [0,1) vs harness threshold 2e-2.
// Overflow: per-block ws list stores (dst<<5|b, src) and phase2 applies with full
// f32 gather (rare); panic (> OVCAP) -> re-stream bucket edges (idempotent max).

typedef int v4i __attribute__((ext_vector_type(4)));

#define NB1 512
#define TH1 1024
#define TH2 1024
#define QCAP 15
#define CSHIFT 12
#define MAXNBKT 448
#define OVCAP 16384

__device__ __forceinline__ unsigned int bf16_rne(float v) {
    unsigned int u = __float_as_uint(v);
    return (u + 0x7FFFu + ((u >> 16) & 1u)) >> 16;
}

__global__ __launch_bounds__(TH1)
void phase1_kernel(const int* __restrict__ edge_index, // [2][E]
                   const int* __restrict__ etype,      // [E]
                   const int* __restrict__ r_index,    // [B]
                   const float* __restrict__ h,        // [B][N]
                   unsigned int* __restrict__ ovcnt,   // [NB1] raw counts
                   uint2* __restrict__ ovrec,          // [NB1][OVCAP]
                   unsigned int* __restrict__ store,   // [nbkt][NB1][16]
                   int B, int N, int E, int nchunk, int nbkt) {
    __shared__ unsigned int smask[64];
    __shared__ unsigned int lcnt[MAXNBKT];
    __shared__ unsigned int lq[MAXNBKT * QCAP];
    __shared__ unsigned int sov;

    const int t = threadIdx.x;
    const int bid = blockIdx.x;
    if (t < 64) {
        unsigned int m = 0;
        for (int b = 0; b < B; ++b)
            if (r_index[b] == t) m |= (1u << b);
        smask[t] = m;
    }
    for (int i = t; i < nbkt; i += TH1) lcnt[i] = 0;
    if (t == 0) sov = 0;
    __syncthreads();

    const int* __restrict__ src = edge_index;
    const int* __restrict__ dst = edge_index + E;
    const unsigned int cmask = (1u << CSHIFT) - 1u;
    const int nq = E >> 2;

    for (int q = bid * TH1 + t; q < nq; q += NB1 * TH1) {
        v4i tv = reinterpret_cast<const v4i*>(etype)[q];
        v4i sv = reinterpret_cast<const v4i*>(src)[q];
        v4i dv = reinterpret_cast<const v4i*>(dst)[q];
        #pragma unroll
        for (int i = 0; i < 4; ++i) {
            unsigned int ty = (unsigned int)tv[i];
            unsigned int m = (ty < 64u) ? smask[ty] : 0u;
            if (!m) continue;
            unsigned int d = (unsigned int)dv[i];
            unsigned int s = (unsigned int)sv[i];
            unsigned int ldst = (d & cmask) << 16;
            int cb = (int)(d >> CSHIFT);
            do {
                int b = __builtin_ctz(m); m &= m - 1;
                float v = h[(size_t)b * N + s];
                if (v <= 0.0f) continue;   // can never beat the 0 floor
                unsigned int rec = ldst | bf16_rne(v);
                int bkt = b * nchunk + cb;
                unsigned int pos = atomicAdd(&lcnt[bkt], 1u);
                if (pos < QCAP) {
                    lq[bkt * QCAP + pos] = rec;
                } else {
                    unsigned int p2 = atomicAdd(&sov, 1u);
                    if (p2 < OVCAP) {
                        uint2 rr; rr.x = (d << 5) | (unsigned int)b; rr.y = s;
                        ovrec[(size_t)bid * OVCAP + p2] = rr;
                    } // beyond OVCAP: dropped; raw count > OVCAP triggers panic re-stream
                }
            } while (m);
        }
    }
    if (bid == 0) {  // tail edges (E % 4)
        for (int e = (nq << 2) + t; e < E; e += TH1) {
            unsigned int ty = (unsigned int)etype[e];
            unsigned int m = (ty < 64u) ? smask[ty] : 0u;
            unsigned int d = (unsigned int)dst[e];
            unsigned int s = (unsigned int)src[e];
            unsigned int ldst = (d & cmask) << 16;
            int cb = (int)(d >> CSHIFT);
            while (m) {
                int b = __builtin_ctz(m); m &= m - 1;
                float v = h[(size_t)b * N + s];
                if (v <= 0.0f) continue;
                unsigned int rec = ldst | bf16_rne(v);
                int bkt = b * nchunk + cb;
                unsigned int pos = atomicAdd(&lcnt[bkt], 1u);
                if (pos < QCAP) {
                    lq[bkt * QCAP + pos] = rec;
                } else {
                    unsigned int p2 = atomicAdd(&sov, 1u);
                    if (p2 < OVCAP) {
                        uint2 rr; rr.x = (d << 5) | (unsigned int)b; rr.y = s;
                        ovrec[(size_t)bid * OVCAP + p2] = rr;
                    }
                }
            }
        }
    }
    __syncthreads();

    if (t == 0) ovcnt[bid] = sov;  // raw (not clamped): >OVCAP means panic

    // Flush: each bucket -> one full 64B line. 16 lanes/bucket, 4 buckets/wave.
    const int wid = t >> 6, lane = t & 63;
    const int sub = lane >> 4, word = lane & 15;
    for (int k0 = wid * 4; k0 < nbkt; k0 += (TH1 / 64) * 4) {
        int k = k0 + sub;
        if (k < nbkt) {
            unsigned int n = lcnt[k]; if (n > QCAP) n = QCAP;
            unsigned int val = (word == 0) ? n : lq[k * QCAP + (word - 1)];
            store[((size_t)k * NB1 + bid) * 16 + word] = val;
        }
    }
}

__global__ __launch_bounds__(TH2)
void phase2_kernel(const float* __restrict__ h,
                   const unsigned int* __restrict__ store,
                   const unsigned int* __restrict__ ovcnt,
                   const uint2* __restrict__ ovrec,
                   const int* __restrict__ edge_index,
                   const int* __restrict__ etype,
                   const int* __restrict__ r_index,
                   int B, int N, int E, int nchunk,
                   int* __restrict__ out) {
    __shared__ int slice[1 << CSHIFT];  // 16KB
    __shared__ int spanic;

    const int t = threadIdx.x;
    // XCD-locality decode: blocks with the same batch b land on the same XCD
    // (bid % 8 heuristic; B % 8 == 0 guarded at launch).
    const int b = blockIdx.x % B;
    const int c = blockIdx.x / B;
    const int k = b * nchunk + c;       // bucket (store layout unchanged)
    const int csz = 1 << CSHIFT;
    const unsigned int cmask = (1u << CSHIFT) - 1u;

    for (int i = t; i < csz; i += TH2) slice[i] = 0;
    if (t == 0) spanic = 0;
    __syncthreads();

    const unsigned int* __restrict__ base = store + (size_t)k * NB1 * 16;
    const float* __restrict__ hb = h + (size_t)b * N;

    // Wave-shaped segment apply: lane reads word (t&15) of segment (t>>4).
    // No gathers: record carries the bf16 value; bf16<<16 is a positive-f32 bit
    // pattern so integer max == float max.
    const int lane16 = t & 15;
    const int srcLane = (t & 63) & ~15;
    #pragma unroll 2
    for (int pass = 0; pass < NB1 / (TH2 / 16); ++pass) {
        int seg = pass * (TH2 / 16) + (t >> 4);
        unsigned int w = base[(size_t)seg * 16 + lane16];
        unsigned int n = (unsigned int)__shfl((int)w, srcLane, 64);
        if (n > QCAP) n = QCAP;
        if (lane16 >= 1 && (unsigned int)lane16 <= n) {
            int ld = (int)(w >> 16);
            atomicMax(&slice[ld], (int)(w << 16));
        }
    }

    // Overflow lists: thread r owns list r (counts ~0 in practice; full f32 gather).
    for (int r = t; r < NB1; r += TH2) {
        unsigned int raw = ovcnt[r];
        if (raw > OVCAP) { atomicOr(&spanic, 1); raw = OVCAP; }
        const uint2* __restrict__ rp = ovrec + (size_t)r * OVCAP;
        for (unsigned int i = 0; i < raw; ++i) {
            uint2 rr = rp[i];
            int bb = (int)(rr.x & 31u);
            unsigned int d = rr.x >> 5;
            if (bb == b && (int)(d >> CSHIFT) == c)
                atomicMax(&slice[d & cmask], __float_as_int(hb[rr.y]));
        }
    }
    __syncthreads();

    if (spanic) {  // ultra-rare: re-stream all edges for this bucket (idempotent max)
        const int rb = r_index[b];
        const int* __restrict__ src = edge_index;
        const int* __restrict__ dst = edge_index + E;
        for (int e = t; e < E; e += TH2) {
            if (etype[e] == rb) {
                unsigned int d = (unsigned int)dst[e];
                if ((int)(d >> CSHIFT) == c)
                    atomicMax(&slice[d & cmask], __float_as_int(hb[src[e]]));
            }
        }
        __syncthreads();
    }

    // Plain coalesced store (out never read; covers clamp floor + empty segments).
    const int d0 = c << CSHIFT;
    int cnt = N - d0; if (cnt > csz) cnt = csz;
    int* __restrict__ ob = out + (size_t)b * N + d0;
    for (int i = t; i < cnt; i += TH2) ob[i] = slice[i];
}

// ===== Fallback for unsupported shapes / tiny ws =====

__global__ __launch_bounds__(256)
void zero_out_kernel(int* __restrict__ out, int n) {
    int i = (blockIdx.x * 256 + threadIdx.x) * 4;
    if (i + 3 < n) {
        v4i z = {0, 0, 0, 0};
        *reinterpret_cast<v4i*>(out + i) = z;
    } else {
        for (int j = i; j < n && j >= 0; ++j) out[j] = 0;
    }
}

__global__ __launch_bounds__(256)
void traverse_direct(const float* __restrict__ h,
                     const int* __restrict__ edge_index,
                     const int* __restrict__ etype,
                     const int* __restrict__ r_index,
                     int* __restrict__ out, int B, int N, int E) {
    __shared__ unsigned int smask[64];
    if (threadIdx.x < 64) {
        unsigned int m = 0;
        for (int b = 0; b < B; ++b)
            if (r_index[b] == (int)threadIdx.x) m |= (1u << b);
        smask[threadIdx.x] = m;
    }
    __syncthreads();
    const int* __restrict__ src = edge_index;
    const int* __restrict__ dst = edge_index + E;
    int e = blockIdx.x * blockDim.x + threadIdx.x;
    if (e < E) {
        unsigned int ty = (unsigned int)etype[e];
        unsigned int m = (ty < 64u) ? smask[ty] : 0u;
        while (m) {
            int b = __builtin_ctz(m); m &= m - 1;
            float v = h[(size_t)b * N + src[e]];
            atomicMax(out + (size_t)b * N + dst[e], __float_as_int(v));
        }
    }
}

extern "C" void kernel_launch(void* const* d_in, const int* in_sizes, int n_in,
                              void* d_out, int out_size, void* d_ws, size_t ws_size,
                              hipStream_t stream) {
    const float* h          = (const float*)d_in[0];
    const int*   edge_index = (const int*)d_in[1];
    const int*   etype      = (const int*)d_in[2];
    const int*   r_index    = (const int*)d_in[3];

    const int B = in_sizes[3];
    const int N = in_sizes[0] / B;
    const int E = in_sizes[2];
    const int nchunk = (N + (1 << CSHIFT) - 1) >> CSHIFT;
    const int nbkt = B * nchunk;
    int* out_i = (int*)d_out;

    // ws layout: ovcnt u32[NB1] (4KB pad) | store [nbkt][NB1][16] u32 | ovrec [NB1][OVCAP] uint2
    unsigned int* ovcnt = (unsigned int*)d_ws;
    unsigned int* store = ovcnt + 1024;
    const size_t store_words = (size_t)(nbkt > 0 ? nbkt : 1) * NB1 * 16;
    uint2* ovrec = (uint2*)(store + store_words);
    const size_t need_ws = 4096 + store_words * 4 + (size_t)NB1 * OVCAP * 8;

    const bool fast = (N <= (1 << 17)) && (B <= 32) && (B % 8 == 0) && (nbkt >= 1) &&
                      (nbkt <= MAXNBKT) && (ws_size >= need_ws) && (E >= 4) &&
                      (out_size == B * N);
    if (fast) {
        phase1_kernel<<<NB1, TH1, 0, stream>>>(
            edge_index, etype, r_index, h, ovcnt, ovrec, store,
            B, N, E, nchunk, nbkt);
        phase2_kernel<<<nbkt, TH2, 0, stream>>>(
            h, store, ovcnt, ovrec, edge_index, etype, r_index,
            B, N, E, nchunk, out_i);
    } else {
        const int nz = (out_size + 1023) / 1024;
        zero_out_kernel<<<nz, 256, 0, stream>>>(out_i, out_size);
        traverse_direct<<<(E + 255) / 256, 256, 0, stream>>>(
            h, edge_index, etype, r_index, out_i, B, N, E);
    }
}

// Round 18
// 26.038 us; speedup vs baseline: 1.1854x; 1.1854x over previous
//
#include <hip/hip_runtime.h>

// SymbolicTraversal: out[b, n] = max(0, max_{e: type[e]==r_index[b], dst[e]==n} h[b, src[e]])
//
// R17: R15 (best, 26.4us) + countless segments.
//   Segments are 16 records, NO count word; empty slots = 0xFFFFFFFF sentinel
//   (legit records < 0x20000000). Phase2 apply: load -> validity compare -> gather
//   -> LDS atomicMax. No shfl count broadcast, no leader branch.
//   phase1: 512 x 1024, plain-load edge streams (R15), relation->batch bitmask,
//           LDS queues -> 64B segment flush, no global atomics.
//   phase2: 400 x 1024, batch-major decode (XCD-local gathers, R13), wave-shaped
//           scan, 16KB LDS slice, plain coalesced store (out never read).
// Record: ((dst & 4095) << 17) | src  (needs N <= 2^17, guarded).
// Overflow: per-block ws list; panic (> OVCAP) -> re-stream bucket edges (idempotent).

typedef int v4i __attribute__((ext_vector_type(4)));

#define NB1 512
#define TH1 1024
#define TH2 1024
#define QCAP 16
#define CSHIFT 12
#define MAXNBKT 448
#define OVCAP 16384
#define EMPTY 0xFFFFFFFFu

__global__ __launch_bounds__(TH1)
void phase1_kernel(const int* __restrict__ edge_index, // [2][E]
                   const int* __restrict__ etype,      // [E]
                   const int* __restrict__ r_index,    // [B]
                   unsigned int* __restrict__ ovcnt,   // [NB1] raw counts
                   uint2* __restrict__ ovrec,          // [NB1][OVCAP]
                   unsigned int* __restrict__ store,   // [nbkt][NB1][16]
                   int B, int N, int E, int nchunk, int nbkt) {
    __shared__ unsigned int smask[64];
    __shared__ unsigned int lcnt[MAXNBKT];
    __shared__ unsigned int lq[MAXNBKT * QCAP];
    __shared__ unsigned int sov;

    const int t = threadIdx.x;
    const int bid = blockIdx.x;
    if (t < 64) {
        unsigned int m = 0;
        for (int b = 0; b < B; ++b)
            if (r_index[b] == t) m |= (1u << b);
        smask[t] = m;
    }
    for (int i = t; i < nbkt; i += TH1) lcnt[i] = 0;
    if (t == 0) sov = 0;
    __syncthreads();

    const int* __restrict__ src = edge_index;
    const int* __restrict__ dst = edge_index + E;
    const unsigned int cmask = (1u << CSHIFT) - 1u;
    const int nq = E >> 2;

    for (int q = bid * TH1 + t; q < nq; q += NB1 * TH1) {
        v4i tv = reinterpret_cast<const v4i*>(etype)[q];
        v4i sv = reinterpret_cast<const v4i*>(src)[q];
        v4i dv = reinterpret_cast<const v4i*>(dst)[q];
        #pragma unroll
        for (int i = 0; i < 4; ++i) {
            unsigned int ty = (unsigned int)tv[i];
            unsigned int m = (ty < 64u) ? smask[ty] : 0u;
            if (!m) continue;
            unsigned int d = (unsigned int)dv[i];
            unsigned int s = (unsigned int)sv[i];
            unsigned int rec = ((d & cmask) << 17) | s;
            int cb = (int)(d >> CSHIFT);
            do {
                int b = __builtin_ctz(m); m &= m - 1;
                int bkt = b * nchunk + cb;
                unsigned int pos = atomicAdd(&lcnt[bkt], 1u);
                if (pos < QCAP) {
                    lq[bkt * QCAP + pos] = rec;
                } else {
                    unsigned int p2 = atomicAdd(&sov, 1u);
                    if (p2 < OVCAP) {
                        uint2 rr; rr.x = (d << 5) | (unsigned int)b; rr.y = s;
                        ovrec[(size_t)bid * OVCAP + p2] = rr;
                    } // beyond OVCAP: dropped; raw count > OVCAP triggers panic re-stream
                }
            } while (m);
        }
    }
    if (bid == 0) {  // tail edges (E % 4)
        for (int e = (nq << 2) + t; e < E; e += TH1) {
            unsigned int ty = (unsigned int)etype[e];
            unsigned int m = (ty < 64u) ? smask[ty] : 0u;
            unsigned int d = (unsigned int)dst[e];
            unsigned int s = (unsigned int)src[e];
            unsigned int rec = ((d & cmask) << 17) | s;
            int cb = (int)(d >> CSHIFT);
            while (m) {
                int b = __builtin_ctz(m); m &= m - 1;
                int bkt = b * nchunk + cb;
                unsigned int pos = atomicAdd(&lcnt[bkt], 1u);
                if (pos < QCAP) {
                    lq[bkt * QCAP + pos] = rec;
                } else {
                    unsigned int p2 = atomicAdd(&sov, 1u);
                    if (p2 < OVCAP) {
                        uint2 rr; rr.x = (d << 5) | (unsigned int)b; rr.y = s;
                        ovrec[(size_t)bid * OVCAP + p2] = rr;
                    }
                }
            }
        }
    }
    __syncthreads();

    if (t == 0) ovcnt[bid] = sov;  // raw (not clamped): >OVCAP means panic

    // Flush: each bucket -> one full 64B line of records (empty slots = sentinel).
    // 16 lanes/bucket, 4 buckets/wave.
    const int wid = t >> 6, lane = t & 63;
    const int sub = lane >> 4, word = lane & 15;
    for (int k0 = wid * 4; k0 < nbkt; k0 += (TH1 / 64) * 4) {
        int k = k0 + sub;
        if (k < nbkt) {
            unsigned int n = lcnt[k]; if (n > QCAP) n = QCAP;
            unsigned int val = ((unsigned int)word < n) ? lq[k * QCAP + word] : EMPTY;
            store[((size_t)k * NB1 + bid) * 16 + word] = val;
        }
    }
}

__global__ __launch_bounds__(TH2)
void phase2_kernel(const float* __restrict__ h,
                   const unsigned int* __restrict__ store,
                   const unsigned int* __restrict__ ovcnt,
                   const uint2* __restrict__ ovrec,
                   const int* __restrict__ edge_index,
                   const int* __restrict__ etype,
                   const int* __restrict__ r_index,
                   int B, int N, int E, int nchunk,
                   int* __restrict__ out) {
    __shared__ int slice[1 << CSHIFT];  // 16KB
    __shared__ int spanic;

    const int t = threadIdx.x;
    // XCD-locality decode: blocks with the same batch b land on the same XCD
    // (bid % 8 heuristic; B % 8 == 0 guarded at launch).
    const int b = blockIdx.x % B;
    const int c = blockIdx.x / B;
    const int k = b * nchunk + c;       // bucket (store layout unchanged)
    const int csz = 1 << CSHIFT;
    const unsigned int cmask = (1u << CSHIFT) - 1u;

    for (int i = t; i < csz; i += TH2) slice[i] = 0;
    if (t == 0) spanic = 0;
    __syncthreads();

    const unsigned int* __restrict__ base = store + (size_t)k * NB1 * 16;
    const float* __restrict__ hb = h + (size_t)b * N;

    // Wave-shaped apply: lane reads word (t&15) of segment (t>>4), coalesced.
    // Valid records are < 0x20000000; empty slots are the 0xFFFFFFFF sentinel.
    const int lane16 = t & 15;
    #pragma unroll 2
    for (int pass = 0; pass < NB1 / (TH2 / 16); ++pass) {
        int seg = pass * (TH2 / 16) + (t >> 4);
        unsigned int w = base[(size_t)seg * 16 + lane16];
        if (w < 0x20000000u) {
            int s  = (int)(w & 0x1FFFFu);
            int ld = (int)(w >> 17);
            atomicMax(&slice[ld], __float_as_int(hb[s]));
        }
    }

    // Overflow lists: thread r owns list r (counts ~0 in practice).
    for (int r = t; r < NB1; r += TH2) {
        unsigned int raw = ovcnt[r];
        if (raw > OVCAP) { atomicOr(&spanic, 1); raw = OVCAP; }
        const uint2* __restrict__ rp = ovrec + (size_t)r * OVCAP;
        for (unsigned int i = 0; i < raw; ++i) {
            uint2 rr = rp[i];
            int bb = (int)(rr.x & 31u);
            unsigned int d = rr.x >> 5;
            if (bb == b && (int)(d >> CSHIFT) == c)
                atomicMax(&slice[d & cmask], __float_as_int(hb[rr.y]));
        }
    }
    __syncthreads();

    if (spanic) {  // ultra-rare: re-stream all edges for this bucket (idempotent max)
        const int rb = r_index[b];
        const int* __restrict__ src = edge_index;
        const int* __restrict__ dst = edge_index + E;
        for (int e = t; e < E; e += TH2) {
            if (etype[e] == rb) {
                unsigned int d = (unsigned int)dst[e];
                if ((int)(d >> CSHIFT) == c)
                    atomicMax(&slice[d & cmask], __float_as_int(hb[src[e]]));
            }
        }
        __syncthreads();
    }

    // Plain coalesced store (out never read; covers clamp floor + empty segments).
    const int d0 = c << CSHIFT;
    int cnt = N - d0; if (cnt > csz) cnt = csz;
    int* __restrict__ ob = out + (size_t)b * N + d0;
    for (int i = t; i < cnt; i += TH2) ob[i] = slice[i];
}

// ===== Fallback for unsupported shapes / tiny ws =====

__global__ __launch_bounds__(256)
void zero_out_kernel(int* __restrict__ out, int n) {
    int i = (blockIdx.x * 256 + threadIdx.x) * 4;
    if (i + 3 < n) {
        v4i z = {0, 0, 0, 0};
        *reinterpret_cast<v4i*>(out + i) = z;
    } else {
        for (int j = i; j < n && j >= 0; ++j) out[j] = 0;
    }
}

__global__ __launch_bounds__(256)
void traverse_direct(const float* __restrict__ h,
                     const int* __restrict__ edge_index,
                     const int* __restrict__ etype,
                     const int* __restrict__ r_index,
                     int* __restrict__ out, int B, int N, int E) {
    __shared__ unsigned int smask[64];
    if (threadIdx.x < 64) {
        unsigned int m = 0;
        for (int b = 0; b < B; ++b)
            if (r_index[b] == (int)threadIdx.x) m |= (1u << b);
        smask[threadIdx.x] = m;
    }
    __syncthreads();
    const int* __restrict__ src = edge_index;
    const int* __restrict__ dst = edge_index + E;
    int e = blockIdx.x * blockDim.x + threadIdx.x;
    if (e < E) {
        unsigned int ty = (unsigned int)etype[e];
        unsigned int m = (ty < 64u) ? smask[ty] : 0u;
        while (m) {
            int b = __builtin_ctz(m); m &= m - 1;
            float v = h[(size_t)b * N + src[e]];
            atomicMax(out + (size_t)b * N + dst[e], __float_as_int(v));
        }
    }
}

extern "C" void kernel_launch(void* const* d_in, const int* in_sizes, int n_in,
                              void* d_out, int out_size, void* d_ws, size_t ws_size,
                              hipStream_t stream) {
    const float* h          = (const float*)d_in[0];
    const int*   edge_index = (const int*)d_in[1];
    const int*   etype      = (const int*)d_in[2];
    const int*   r_index    = (const int*)d_in[3];

    const int B = in_sizes[3];
    const int N = in_sizes[0] / B;
    const int E = in_sizes[2];
    const int nchunk = (N + (1 << CSHIFT) - 1) >> CSHIFT;
    const int nbkt = B * nchunk;
    int* out_i = (int*)d_out;

    // ws layout: ovcnt u32[NB1] (4KB pad) | store [nbkt][NB1][16] u32 | ovrec [NB1][OVCAP] uint2
    unsigned int* ovcnt = (unsigned int*)d_ws;
    unsigned int* store = ovcnt + 1024;
    const size_t store_words = (size_t)(nbkt > 0 ? nbkt : 1) * NB1 * 16;
    uint2* ovrec = (uint2*)(store + store_words);
    const size_t need_ws = 4096 + store_words * 4 + (size_t)NB1 * OVCAP * 8;

    const bool fast = (N <= (1 << 17)) && (B <= 32) && (B % 8 == 0) && (nbkt >= 1) &&
                      (nbkt <= MAXNBKT) && (ws_size >= need_ws) && (E >= 4) &&
                      (out_size == B * N);
    if (fast) {
        phase1_kernel<<<NB1, TH1, 0, stream>>>(
            edge_index, etype, r_index, ovcnt, ovrec, store,
            B, N, E, nchunk, nbkt);
        phase2_kernel<<<nbkt, TH2, 0, stream>>>(
            h, store, ovcnt, ovrec, edge_index, etype, r_index,
            B, N, E, nchunk, out_i);
    } else {
        const int nz = (out_size + 1023) / 1024;
        zero_out_kernel<<<nz, 256, 0, stream>>>(out_i, out_size);
        traverse_direct<<<(E + 255) / 256, 256, 0, stream>>>(
            h, edge_index, etype, r_index, out_i, B, N, E);
    }
}

// Round 19
// 25.385 us; speedup vs baseline: 1.2159x; 1.0257x over previous
//
#include <hip/hip_runtime.h>

// SymbolicTraversal: out[b, n] = max(0, max_{e: type[e]==r_index[b], dst[e]==n} h[b, src[e]])
//
// R18: R17 (best, 26.0us) + two traffic shaves.
//   (1) NB1 512 -> 384: segment lambda 3.9 -> 5.1 (overflow still ~0), store/scan
//       traffic 13.1 -> 9.8 MB each way, phase1 keeps 1.5 blocks/CU.
//   (2) phase2 out store vectorized (v4i, 16B/lane).
//   Structure: countless 64B segments (16 records, empty = 0xFFFFFFFF sentinel,
//   valid records < 0x20000000); phase1 plain-load streams + LDS queues, no global
//   atomics; phase2 batch-major decode (XCD-local gathers), wave-shaped scan, 16KB
//   LDS slice, coalesced store (out never read).
// Record: ((dst & 4095) << 17) | src  (needs N <= 2^17, guarded).
// Overflow: per-block ws list; panic (> OVCAP) -> re-stream bucket edges (idempotent).

typedef int v4i __attribute__((ext_vector_type(4)));

#define NB1 384
#define TH1 1024
#define TH2 1024
#define QCAP 16
#define CSHIFT 12
#define MAXNBKT 448
#define OVCAP 16384
#define EMPTY 0xFFFFFFFFu

__global__ __launch_bounds__(TH1)
void phase1_kernel(const int* __restrict__ edge_index, // [2][E]
                   const int* __restrict__ etype,      // [E]
                   const int* __restrict__ r_index,    // [B]
                   unsigned int* __restrict__ ovcnt,   // [NB1] raw counts
                   uint2* __restrict__ ovrec,          // [NB1][OVCAP]
                   unsigned int* __restrict__ store,   // [nbkt][NB1][16]
                   int B, int N, int E, int nchunk, int nbkt) {
    __shared__ unsigned int smask[64];
    __shared__ unsigned int lcnt[MAXNBKT];
    __shared__ unsigned int lq[MAXNBKT * QCAP];
    __shared__ unsigned int sov;

    const int t = threadIdx.x;
    const int bid = blockIdx.x;
    if (t < 64) {
        unsigned int m = 0;
        for (int b = 0; b < B; ++b)
            if (r_index[b] == t) m |= (1u << b);
        smask[t] = m;
    }
    for (int i = t; i < nbkt; i += TH1) lcnt[i] = 0;
    if (t == 0) sov = 0;
    __syncthreads();

    const int* __restrict__ src = edge_index;
    const int* __restrict__ dst = edge_index + E;
    const unsigned int cmask = (1u << CSHIFT) - 1u;
    const int nq = E >> 2;

    for (int q = bid * TH1 + t; q < nq; q += NB1 * TH1) {
        v4i tv = reinterpret_cast<const v4i*>(etype)[q];
        v4i sv = reinterpret_cast<const v4i*>(src)[q];
        v4i dv = reinterpret_cast<const v4i*>(dst)[q];
        #pragma unroll
        for (int i = 0; i < 4; ++i) {
            unsigned int ty = (unsigned int)tv[i];
            unsigned int m = (ty < 64u) ? smask[ty] : 0u;
            if (!m) continue;
            unsigned int d = (unsigned int)dv[i];
            unsigned int s = (unsigned int)sv[i];
            unsigned int rec = ((d & cmask) << 17) | s;
            int cb = (int)(d >> CSHIFT);
            do {
                int b = __builtin_ctz(m); m &= m - 1;
                int bkt = b * nchunk + cb;
                unsigned int pos = atomicAdd(&lcnt[bkt], 1u);
                if (pos < QCAP) {
                    lq[bkt * QCAP + pos] = rec;
                } else {
                    unsigned int p2 = atomicAdd(&sov, 1u);
                    if (p2 < OVCAP) {
                        uint2 rr; rr.x = (d << 5) | (unsigned int)b; rr.y = s;
                        ovrec[(size_t)bid * OVCAP + p2] = rr;
                    } // beyond OVCAP: dropped; raw count > OVCAP triggers panic re-stream
                }
            } while (m);
        }
    }
    if (bid == 0) {  // tail edges (E % 4)
        for (int e = (nq << 2) + t; e < E; e += TH1) {
            unsigned int ty = (unsigned int)etype[e];
            unsigned int m = (ty < 64u) ? smask[ty] : 0u;
            unsigned int d = (unsigned int)dst[e];
            unsigned int s = (unsigned int)src[e];
            unsigned int rec = ((d & cmask) << 17) | s;
            int cb = (int)(d >> CSHIFT);
            while (m) {
                int b = __builtin_ctz(m); m &= m - 1;
                int bkt = b * nchunk + cb;
                unsigned int pos = atomicAdd(&lcnt[bkt], 1u);
                if (pos < QCAP) {
                    lq[bkt * QCAP + pos] = rec;
                } else {
                    unsigned int p2 = atomicAdd(&sov, 1u);
                    if (p2 < OVCAP) {
                        uint2 rr; rr.x = (d << 5) | (unsigned int)b; rr.y = s;
                        ovrec[(size_t)bid * OVCAP + p2] = rr;
                    }
                }
            }
        }
    }
    __syncthreads();

    if (t == 0) ovcnt[bid] = sov;  // raw (not clamped): >OVCAP means panic

    // Flush: each bucket -> one full 64B line of records (empty slots = sentinel).
    // 16 lanes/bucket, 4 buckets/wave.
    const int wid = t >> 6, lane = t & 63;
    const int sub = lane >> 4, word = lane & 15;
    for (int k0 = wid * 4; k0 < nbkt; k0 += (TH1 / 64) * 4) {
        int k = k0 + sub;
        if (k < nbkt) {
            unsigned int n = lcnt[k]; if (n > QCAP) n = QCAP;
            unsigned int val = ((unsigned int)word < n) ? lq[k * QCAP + word] : EMPTY;
            store[((size_t)k * NB1 + bid) * 16 + word] = val;
        }
    }
}

__global__ __launch_bounds__(TH2)
void phase2_kernel(const float* __restrict__ h,
                   const unsigned int* __restrict__ store,
                   const unsigned int* __restrict__ ovcnt,
                   const uint2* __restrict__ ovrec,
                   const int* __restrict__ edge_index,
                   const int* __restrict__ etype,
                   const int* __restrict__ r_index,
                   int B, int N, int E, int nchunk,
                   int* __restrict__ out) {
    __shared__ int slice[1 << CSHIFT];  // 16KB
    __shared__ int spanic;

    const int t = threadIdx.x;
    // XCD-locality decode: blocks with the same batch b land on the same XCD
    // (bid % 8 heuristic; B % 8 == 0 guarded at launch).
    const int b = blockIdx.x % B;
    const int c = blockIdx.x / B;
    const int k = b * nchunk + c;       // bucket (store layout unchanged)
    const int csz = 1 << CSHIFT;
    const unsigned int cmask = (1u << CSHIFT) - 1u;

    for (int i = t; i < csz; i += TH2) slice[i] = 0;
    if (t == 0) spanic = 0;
    __syncthreads();

    const unsigned int* __restrict__ base = store + (size_t)k * NB1 * 16;
    const float* __restrict__ hb = h + (size_t)b * N;

    // Wave-shaped apply: lane reads word (t&15) of segment (t>>4), coalesced.
    // Valid records are < 0x20000000; empty slots are the 0xFFFFFFFF sentinel.
    const int lane16 = t & 15;
    #pragma unroll 2
    for (int pass = 0; pass < NB1 / (TH2 / 16); ++pass) {
        int seg = pass * (TH2 / 16) + (t >> 4);
        unsigned int w = base[(size_t)seg * 16 + lane16];
        if (w < 0x20000000u) {
            int s  = (int)(w & 0x1FFFFu);
            int ld = (int)(w >> 17);
            atomicMax(&slice[ld], __float_as_int(hb[s]));
        }
    }

    // Overflow lists: thread r owns list r (counts ~0 in practice).
    for (int r = t; r < NB1; r += TH2) {
        unsigned int raw = ovcnt[r];
        if (raw > OVCAP) { atomicOr(&spanic, 1); raw = OVCAP; }
        const uint2* __restrict__ rp = ovrec + (size_t)r * OVCAP;
        for (unsigned int i = 0; i < raw; ++i) {
            uint2 rr = rp[i];
            int bb = (int)(rr.x & 31u);
            unsigned int d = rr.x >> 5;
            if (bb == b && (int)(d >> CSHIFT) == c)
                atomicMax(&slice[d & cmask], __float_as_int(hb[rr.y]));
        }
    }
    __syncthreads();

    if (spanic) {  // ultra-rare: re-stream all edges for this bucket (idempotent max)
        const int rb = r_index[b];
        const int* __restrict__ src = edge_index;
        const int* __restrict__ dst = edge_index + E;
        for (int e = t; e < E; e += TH2) {
            if (etype[e] == rb) {
                unsigned int d = (unsigned int)dst[e];
                if ((int)(d >> CSHIFT) == c)
                    atomicMax(&slice[d & cmask], __float_as_int(hb[src[e]]));
            }
        }
        __syncthreads();
    }

    // Vectorized coalesced store (out never read; covers clamp floor + empties).
    const int d0 = c << CSHIFT;
    int cnt = N - d0; if (cnt > csz) cnt = csz;
    int* __restrict__ ob = out + (size_t)b * N + d0;
    const int cnt4 = cnt >> 2;
    for (int i = t; i < cnt4; i += TH2) {
        v4i v = { slice[i*4], slice[i*4+1], slice[i*4+2], slice[i*4+3] };
        *reinterpret_cast<v4i*>(ob + i*4) = v;
    }
    for (int i = (cnt4 << 2) + t; i < cnt; i += TH2) ob[i] = slice[i];
}

// ===== Fallback for unsupported shapes / tiny ws =====

__global__ __launch_bounds__(256)
void zero_out_kernel(int* __restrict__ out, int n) {
    int i = (blockIdx.x * 256 + threadIdx.x) * 4;
    if (i + 3 < n) {
        v4i z = {0, 0, 0, 0};
        *reinterpret_cast<v4i*>(out + i) = z;
    } else {
        for (int j = i; j < n && j >= 0; ++j) out[j] = 0;
    }
}

__global__ __launch_bounds__(256)
void traverse_direct(const float* __restrict__ h,
                     const int* __restrict__ edge_index,
                     const int* __restrict__ etype,
                     const int* __restrict__ r_index,
                     int* __restrict__ out, int B, int N, int E) {
    __shared__ unsigned int smask[64];
    if (threadIdx.x < 64) {
        unsigned int m = 0;
        for (int b = 0; b < B; ++b)
            if (r_index[b] == (int)threadIdx.x) m |= (1u << b);
        smask[threadIdx.x] = m;
    }
    __syncthreads();
    const int* __restrict__ src = edge_index;
    const int* __restrict__ dst = edge_index + E;
    int e = blockIdx.x * blockDim.x + threadIdx.x;
    if (e < E) {
        unsigned int ty = (unsigned int)etype[e];
        unsigned int m = (ty < 64u) ? smask[ty] : 0u;
        while (m) {
            int b = __builtin_ctz(m); m &= m - 1;
            float v = h[(size_t)b * N + src[e]];
            atomicMax(out + (size_t)b * N + dst[e], __float_as_int(v));
        }
    }
}

extern "C" void kernel_launch(void* const* d_in, const int* in_sizes, int n_in,
                              void* d_out, int out_size, void* d_ws, size_t ws_size,
                              hipStream_t stream) {
    const float* h          = (const float*)d_in[0];
    const int*   edge_index = (const int*)d_in[1];
    const int*   etype      = (const int*)d_in[2];
    const int*   r_index    = (const int*)d_in[3];

    const int B = in_sizes[3];
    const int N = in_sizes[0] / B;
    const int E = in_sizes[2];
    const int nchunk = (N + (1 << CSHIFT) - 1) >> CSHIFT;
    const int nbkt = B * nchunk;
    int* out_i = (int*)d_out;

    // ws layout: ovcnt u32[NB1] (4KB pad) | store [nbkt][NB1][16] u32 | ovrec [NB1][OVCAP] uint2
    unsigned int* ovcnt = (unsigned int*)d_ws;
    unsigned int* store = ovcnt + 1024;
    const size_t store_words = (size_t)(nbkt > 0 ? nbkt : 1) * NB1 * 16;
    uint2* ovrec = (uint2*)(store + store_words);
    const size_t need_ws = 4096 + store_words * 4 + (size_t)NB1 * OVCAP * 8;

    const bool fast = (N <= (1 << 17)) && (B <= 32) && (B % 8 == 0) && (nbkt >= 1) &&
                      (nbkt <= MAXNBKT) && (ws_size >= need_ws) && (E >= 4) &&
                      (out_size == B * N);
    if (fast) {
        phase1_kernel<<<NB1, TH1, 0, stream>>>(
            edge_index, etype, r_index, ovcnt, ovrec, store,
            B, N, E, nchunk, nbkt);
        phase2_kernel<<<nbkt, TH2, 0, stream>>>(
            h, store, ovcnt, ovrec, edge_index, etype, r_index,
            B, N, E, nchunk, out_i);
    } else {
        const int nz = (out_size + 1023) / 1024;
        zero_out_kernel<<<nz, 256, 0, stream>>>(out_i, out_size);
        traverse_direct<<<(E + 255) / 256, 256, 0, stream>>>(
            h, edge_index, etype, r_index, out_i, B, N, E);
    }
}